// Round 21
// baseline (547.477 us; speedup 1.0000x reference)
//
#include <hip/hip_runtime.h>

#define N_NODES 100000
#define N_PAD   100032   // 1563 * 64 -- padded node count for guard-free staging
#define N_EDGES 1600000
#define T_STEPS 6
#define FDIM    64
#define SEG     (T_STEPS * N_NODES)
#define C2      0.01f
#define PADF    68   // LDS row stride: 17 quads, 16B-aligned float4 rows
#define NB      ((SEG + 255) / 256)   // scan blocks = 2344
#define RFL __builtin_amdgcn_readfirstlane

// ---- CSR build: counts -> exclusive scan -> fill (verbatim r10, which
// PASSED at absmax 128 -- fill order is numerically safe). Built once. ----

__global__ __launch_bounds__(256) void k_count(
    const int* __restrict__ dst, const int* __restrict__ tix,
    int* __restrict__ cnt_i)
{
  const int e = blockIdx.x * blockDim.x + threadIdx.x;
  if (e >= N_EDGES) return;
  atomicAdd(&cnt_i[tix[e] * N_NODES + dst[e]], 1);
}

__global__ __launch_bounds__(256) void k_scan1(
    const int* __restrict__ cnt_i, int* __restrict__ offs, int* __restrict__ bsum)
{
  __shared__ int sh[256];
  const int gid = blockIdx.x * 256 + threadIdx.x;
  const int v = (gid < SEG) ? cnt_i[gid] : 0;
  sh[threadIdx.x] = v;
  __syncthreads();
  #pragma unroll
  for (int o = 1; o < 256; o <<= 1) {
    const int add = (threadIdx.x >= o) ? sh[threadIdx.x - o] : 0;
    __syncthreads();
    sh[threadIdx.x] += add;
    __syncthreads();
  }
  if (gid < SEG) offs[gid] = sh[threadIdx.x] - v;
  if (threadIdx.x == 255) bsum[blockIdx.x] = sh[255];
}

__global__ __launch_bounds__(256) void k_scan2(int* __restrict__ bsum, int nb)
{
  __shared__ int sh[256];
  __shared__ int carry_sh;
  if (threadIdx.x == 0) carry_sh = 0;
  __syncthreads();
  for (int base = 0; base < nb; base += 256) {
    const int i = base + threadIdx.x;
    const int v = (i < nb) ? bsum[i] : 0;
    sh[threadIdx.x] = v;
    __syncthreads();
    #pragma unroll
    for (int o = 1; o < 256; o <<= 1) {
      const int add = (threadIdx.x >= o) ? sh[threadIdx.x - o] : 0;
      __syncthreads();
      sh[threadIdx.x] += add;
      __syncthreads();
    }
    const int carry = carry_sh;
    if (i < nb) bsum[i] = carry + sh[threadIdx.x] - v;
    __syncthreads();
    if (threadIdx.x == 255) carry_sh = carry + sh[255];
    __syncthreads();
  }
}

__global__ __launch_bounds__(256) void k_scan3(
    const int* __restrict__ cnt_i, const int* __restrict__ bsum,
    int* __restrict__ offs, int* __restrict__ curs, float* __restrict__ cntf)
{
  const int gid = blockIdx.x * 256 + threadIdx.x;
  if (gid >= SEG) return;
  const int o = offs[gid] + bsum[blockIdx.x];
  offs[gid] = o;
  curs[gid] = o;
  cntf[gid] = (float)cnt_i[gid];
  if (gid == 0) offs[SEG] = N_EDGES;
}

__global__ __launch_bounds__(256) void k_fill(
    const int* __restrict__ src, const int* __restrict__ dst,
    const int* __restrict__ tix, int* __restrict__ curs,
    int* __restrict__ csr_src)
{
  const int e = blockIdx.x * blockDim.x + threadIdx.x;
  if (e >= N_EDGES) return;
  const int slot = atomicAdd(&curs[tix[e] * N_NODES + dst[e]], 1);
  csr_src[slot] = src[e];
}

// One wave per NODE, lane = feature, 6 CSR ranges interleaved, SCALARIZED:
// it/et counters in SGPRs (RFL), csr_src[a] is a uniform load -> s_load.
// Unlike the r17 list walker there is NO dependent chain (counters don't
// depend on loads), and csr_src reads are sequential (6.4MB total vs ~205MB
// of random nxt/src line traffic). r10 proved this fill order gives
// absmax 128 with the identical downstream arithmetic.
__global__ __launch_bounds__(256) void k_sum_csr(
    const float* __restrict__ feat, const int* __restrict__ csr_src,
    const int* __restrict__ offs, float* __restrict__ sums)
{
  const int lane = threadIdx.x & 63;
  const int n = blockIdx.x * (blockDim.x >> 6) + (threadIdx.x >> 6);
  if (n >= N_NODES) return;

  int it0 = RFL(offs[0 * N_NODES + n]), et0 = RFL(offs[0 * N_NODES + n + 1]);
  int it1 = RFL(offs[1 * N_NODES + n]), et1 = RFL(offs[1 * N_NODES + n + 1]);
  int it2 = RFL(offs[2 * N_NODES + n]), et2 = RFL(offs[2 * N_NODES + n + 1]);
  int it3 = RFL(offs[3 * N_NODES + n]), et3 = RFL(offs[3 * N_NODES + n + 1]);
  int it4 = RFL(offs[4 * N_NODES + n]), et4 = RFL(offs[4 * N_NODES + n + 1]);
  int it5 = RFL(offs[5 * N_NODES + n]), et5 = RFL(offs[5 * N_NODES + n + 1]);

  float v0 = 0.f, v1 = 0.f, v2 = 0.f, v3 = 0.f, v4 = 0.f, v5 = 0.f;

  while ((it0 < et0) | (it1 < et1) | (it2 < et2) |
         (it3 < et3) | (it4 < et4) | (it5 < et5)) {
    const int a0 = (it0 < et0) ? it0 : 0;
    const int a1 = (it1 < et1) ? it1 : 0;
    const int a2 = (it2 < et2) ? it2 : 0;
    const int a3 = (it3 < et3) ? it3 : 0;
    const int a4 = (it4 < et4) ? it4 : 0;
    const int a5 = (it5 < et5) ? it5 : 0;

    const int s0 = RFL(csr_src[a0]);
    const int s1 = RFL(csr_src[a1]);
    const int s2 = RFL(csr_src[a2]);
    const int s3 = RFL(csr_src[a3]);
    const int s4 = RFL(csr_src[a4]);
    const int s5 = RFL(csr_src[a5]);

    const float f0 = feat[(size_t)s0 * FDIM + lane];
    const float f1 = feat[(size_t)s1 * FDIM + lane];
    const float f2 = feat[(size_t)s2 * FDIM + lane];
    const float f3 = feat[(size_t)s3 * FDIM + lane];
    const float f4 = feat[(size_t)s4 * FDIM + lane];
    const float f5 = feat[(size_t)s5 * FDIM + lane];

    v0 += (it0 < et0) ? f0 : 0.0f;  it0 += (it0 < et0);
    v1 += (it1 < et1) ? f1 : 0.0f;  it1 += (it1 < et1);
    v2 += (it2 < et2) ? f2 : 0.0f;  it2 += (it2 < et2);
    v3 += (it3 < et3) ? f3 : 0.0f;  it3 += (it3 < et3);
    v4 += (it4 < et4) ? f4 : 0.0f;  it4 += (it4 < et4);
    v5 += (it5 < et5) ? f5 : 0.0f;  it5 += (it5 < et5);
  }

  sums[((size_t)0 * N_PAD + n) * FDIM + lane] = v0;
  sums[((size_t)1 * N_PAD + n) * FDIM + lane] = v1;
  sums[((size_t)2 * N_PAD + n) * FDIM + lane] = v2;
  sums[((size_t)3 * N_PAD + n) * FDIM + lane] = v3;
  sums[((size_t)4 * N_PAD + n) * FDIM + lane] = v4;
  sums[((size_t)5 * N_PAD + n) * FDIM + lane] = v5;
}

// ===== VERBATIM r20 gemm (rolled two-plane staging, guard-free N_PAD) =====
template <int OUTF, int JBLK>
__global__ __launch_bounds__(256) void k_gemm_tile2(
    const float* __restrict__ sums, const float* __restrict__ cnt,
    const float* __restrict__ W, const float* __restrict__ bias,
    float* __restrict__ out)
{
  __shared__ float lds[2][64 * PADF];   // 2 planes x 17408 B
  const int tid = threadIdx.x;
  const int lane = tid & 63;
  const int n0 = blockIdx.x * 64;
  const int jb = RFL(tid >> 6) * JBLK;

  int n = n0 + lane;
  const bool valid = (n < N_NODES);
  if (!valid) n = N_NODES - 1;

  float acc[JBLK];
  #pragma unroll
  for (int j = 0; j < JBLK; ++j) acc[j] = bias[jb + j];

  #pragma unroll 1
  for (int tp = 0; tp < T_STEPS / 2; ++tp) {
    __syncthreads();
    float4 reg[8];
    #pragma unroll
    for (int it = 0; it < 8; ++it) {
      const int item = tid + it * 256;
      const int q = item & 15;
      const int u = (item >> 4) & 63;
      const int pl = item >> 10;
      reg[it] = *(const float4*)(sums + ((size_t)(2 * tp + pl) * N_PAD + n0 + u) * FDIM + q * 4);
    }
    #pragma unroll
    for (int it = 0; it < 8; ++it) {
      const int item = tid + it * 256;
      const int q = item & 15;
      const int u = (item >> 4) & 63;
      const int pl = item >> 10;
      *(float4*)(&lds[pl][u * PADF + q * 4]) = reg[it];
    }
    __syncthreads();

    #pragma unroll
    for (int pl = 0; pl < 2; ++pl) {
      const int t = 2 * tp + pl;

      const float c  = cnt[(size_t)t * N_NODES + n];
      const float rc = 1.0f / fmaxf(c, 1.0f);
      const float4* row = (const float4*)(&lds[pl][lane * PADF]);
      float ss = 0.0f;
      #pragma unroll
      for (int q = 0; q < FDIM / 4; ++q) {
        float4 v = row[q];
        float m0 = v.x * rc, m1 = v.y * rc, m2 = v.z * rc, m3 = v.w * rc;
        ss += m0 * m0 + m1 * m1 + m2 * m2 + m3 * m3;
      }
      const float norm = 1.0f - C2 * ss;
      const float s = rc / norm;

      #pragma unroll
      for (int q8 = 0; q8 < FDIM / 8; ++q8) {
        const float4 a = row[q8 * 2 + 0];
        const float4 b4 = row[q8 * 2 + 1];
        const float hv[8] = {a.x, a.y, a.z, a.w, b4.x, b4.y, b4.z, b4.w};
        const float* wr = W + ((size_t)t * FDIM + q8 * 8) * OUTF + jb;
        #pragma unroll
        for (int i = 0; i < 8; ++i) {
          const float hs = hv[i] * s;
          #pragma unroll
          for (int j = 0; j < JBLK; ++j)
            acc[j] = fmaf(hs, wr[i * OUTF + j], acc[j]);
        }
      }
    }
  }

  if (valid) {
    float* o = out + (size_t)n * OUTF + jb;
    #pragma unroll
    for (int j = 0; j < JBLK; ++j) o[j] = fmaxf(acc[j], 0.0f);
  }
}

extern "C" void kernel_launch(void* const* d_in, const int* in_sizes, int n_in,
                              void* d_out, int out_size, void* d_ws, size_t ws_size,
                              hipStream_t stream) {
  const float* x  = (const float*)d_in[0];
  const int*  ei  = (const int*)d_in[1];
  const int*  tix = (const int*)d_in[2];
  const float* W1 = (const float*)d_in[3];
  const float* b1 = (const float*)d_in[4];
  const float* W2 = (const float*)d_in[5];
  const float* b2 = (const float*)d_in[6];

  const int* src = ei;
  const int* dst = ei + N_EDGES;

  // Workspace: cnt_i[SEG] | offs[SEG+1] | bsum[2560] | curs[SEG] | csr_src[NE]
  //          | cntf[SEG] | pad(3) | sums[6*N_PAD*64] | h1[N_PAD*64]
  int*   cnt_i   = (int*)d_ws;
  int*   offs    = cnt_i + SEG;
  int*   bsum    = offs + (SEG + 1);
  int*   curs    = bsum + 2560;
  int*   csr_src = curs + SEG;
  float* cntf    = (float*)(csr_src + N_EDGES);
  float* sums    = cntf + SEG + 3;            // +3 -> 16B-aligned
  float* h1      = sums + (size_t)T_STEPS * N_PAD * FDIM;

  const int sum_grid = (N_NODES + 3) / 4;     // 4 waves/block, wave per node
  const int ngrp     = (N_NODES + 63) / 64;   // 1563 64-node groups

  // CSR build (once, reused by both layers; cntf written once here)
  hipMemsetAsync(cnt_i, 0, (size_t)SEG * sizeof(int), stream);
  k_count<<<(N_EDGES + 255) / 256, 256, 0, stream>>>(dst, tix, cnt_i);
  k_scan1<<<NB, 256, 0, stream>>>(cnt_i, offs, bsum);
  k_scan2<<<1, 256, 0, stream>>>(bsum, NB);
  k_scan3<<<NB, 256, 0, stream>>>(cnt_i, bsum, offs, curs, cntf);
  k_fill<<<(N_EDGES + 255) / 256, 256, 0, stream>>>(src, dst, tix, curs, csr_src);

  // Layer 1
  k_sum_csr<<<sum_grid, 256, 0, stream>>>(x, csr_src, offs, sums);
  k_gemm_tile2<64, 16><<<ngrp, 256, 0, stream>>>(sums, cntf, W1, b1, h1);

  // Layer 2 (same CSR, same cntf)
  k_sum_csr<<<sum_grid, 256, 0, stream>>>(h1, csr_src, offs, sums);
  k_gemm_tile2<16, 4><<<ngrp, 256, 0, stream>>>(sums, cntf, W2, b2, (float*)d_out);
}

// Round 22
// 424.943 us; speedup vs baseline: 1.2884x; 1.2884x over previous
//
#include <hip/hip_runtime.h>

#define N_NODES 100000
#define N_PAD   100032   // 1563 * 64 -- padded node count for guard-free staging
#define N_EDGES 1600000
#define T_STEPS 6
#define FDIM    64
#define SEG     (T_STEPS * N_NODES)
#define C2      0.01f
#define PADF    68   // LDS row stride: 17 quads, 16B-aligned float4 rows
#define RFL __builtin_amdgcn_readfirstlane

// Build per-(t,dst)-segment linked lists. One atomicExch per edge, and pack
// {src, next} into ONE int2 so the walker does a single 8B load per step
// (r20 post-mortem: src[a] + nxt[a] hit two random 64B lines each -> ~205MB
// of pure line overfetch, the dominant k_sum6 cost).
__global__ __launch_bounds__(256) void k_build(
    const int* __restrict__ src, const int* __restrict__ dst,
    const int* __restrict__ tix, int* __restrict__ head,
    int2* __restrict__ edat)
{
  const int e = blockIdx.x * blockDim.x + threadIdx.x;
  if (e >= N_EDGES) return;
  const int key = tix[e] * N_NODES + dst[e];
  const int prev = atomicExch(&head[key], e);
  edat[e] = make_int2(src[e], prev);
}

// r20 k_sum6 (scalarized 6-chain interleave, measured best 131us), with the
// two random index loads fused into one 8B load: s=edat[a].x, next=edat[a].y.
// Same values, same list order, same add order -> bit-identical output.
__global__ __launch_bounds__(256) void k_sum6(
    const float* __restrict__ feat, const int2* __restrict__ edat,
    const int* __restrict__ head, float* __restrict__ sums,
    float* __restrict__ cnt)
{
  const int lane = threadIdx.x & 63;
  const int n = blockIdx.x * (blockDim.x >> 6) + (threadIdx.x >> 6);
  if (n >= N_NODES) return;

  int e0 = RFL(head[(size_t)0 * N_NODES + n]);
  int e1 = RFL(head[(size_t)1 * N_NODES + n]);
  int e2 = RFL(head[(size_t)2 * N_NODES + n]);
  int e3 = RFL(head[(size_t)3 * N_NODES + n]);
  int e4 = RFL(head[(size_t)4 * N_NODES + n]);
  int e5 = RFL(head[(size_t)5 * N_NODES + n]);

  float v0 = 0.f, v1 = 0.f, v2 = 0.f, v3 = 0.f, v4 = 0.f, v5 = 0.f;
  int c0 = 0, c1 = 0, c2 = 0, c3 = 0, c4 = 0, c5 = 0;

  while ((e0 >= 0) | (e1 >= 0) | (e2 >= 0) | (e3 >= 0) | (e4 >= 0) | (e5 >= 0)) {
    const int a0 = e0 < 0 ? 0 : e0, a1 = e1 < 0 ? 0 : e1, a2 = e2 < 0 ? 0 : e2;
    const int a3 = e3 < 0 ? 0 : e3, a4 = e4 < 0 ? 0 : e4, a5 = e5 < 0 ? 0 : e5;

    const int2 d0 = edat[a0];
    const int2 d1 = edat[a1];
    const int2 d2 = edat[a2];
    const int2 d3 = edat[a3];
    const int2 d4 = edat[a4];
    const int2 d5 = edat[a5];

    const int s0 = RFL(d0.x), x0 = RFL(d0.y);
    const int s1 = RFL(d1.x), x1 = RFL(d1.y);
    const int s2 = RFL(d2.x), x2 = RFL(d2.y);
    const int s3 = RFL(d3.x), x3 = RFL(d3.y);
    const int s4 = RFL(d4.x), x4 = RFL(d4.y);
    const int s5 = RFL(d5.x), x5 = RFL(d5.y);

    const float f0 = feat[(size_t)s0 * FDIM + lane];
    const float f1 = feat[(size_t)s1 * FDIM + lane];
    const float f2 = feat[(size_t)s2 * FDIM + lane];
    const float f3 = feat[(size_t)s3 * FDIM + lane];
    const float f4 = feat[(size_t)s4 * FDIM + lane];
    const float f5 = feat[(size_t)s5 * FDIM + lane];

    v0 += (e0 >= 0) ? f0 : 0.0f;  c0 += (e0 >= 0);  e0 = (e0 >= 0) ? x0 : -1;
    v1 += (e1 >= 0) ? f1 : 0.0f;  c1 += (e1 >= 0);  e1 = (e1 >= 0) ? x1 : -1;
    v2 += (e2 >= 0) ? f2 : 0.0f;  c2 += (e2 >= 0);  e2 = (e2 >= 0) ? x2 : -1;
    v3 += (e3 >= 0) ? f3 : 0.0f;  c3 += (e3 >= 0);  e3 = (e3 >= 0) ? x3 : -1;
    v4 += (e4 >= 0) ? f4 : 0.0f;  c4 += (e4 >= 0);  e4 = (e4 >= 0) ? x4 : -1;
    v5 += (e5 >= 0) ? f5 : 0.0f;  c5 += (e5 >= 0);  e5 = (e5 >= 0) ? x5 : -1;
  }

  sums[((size_t)0 * N_PAD + n) * FDIM + lane] = v0;
  sums[((size_t)1 * N_PAD + n) * FDIM + lane] = v1;
  sums[((size_t)2 * N_PAD + n) * FDIM + lane] = v2;
  sums[((size_t)3 * N_PAD + n) * FDIM + lane] = v3;
  sums[((size_t)4 * N_PAD + n) * FDIM + lane] = v4;
  sums[((size_t)5 * N_PAD + n) * FDIM + lane] = v5;
  if (lane == 0) {
    cnt[(size_t)0 * N_NODES + n] = (float)c0;
    cnt[(size_t)1 * N_NODES + n] = (float)c1;
    cnt[(size_t)2 * N_NODES + n] = (float)c2;
    cnt[(size_t)3 * N_NODES + n] = (float)c3;
    cnt[(size_t)4 * N_NODES + n] = (float)c4;
    cnt[(size_t)5 * N_NODES + n] = (float)c5;
  }
}

// ===== VERBATIM r20 gemm (rolled two-plane staging, guard-free N_PAD;
// sums back at a 256B-aligned offset -- r21's 16B-misaligned sums
// coincided with the 87->125us gemm regression). =====
template <int OUTF, int JBLK>
__global__ __launch_bounds__(256) void k_gemm_tile2(
    const float* __restrict__ sums, const float* __restrict__ cnt,
    const float* __restrict__ W, const float* __restrict__ bias,
    float* __restrict__ out)
{
  __shared__ float lds[2][64 * PADF];   // 2 planes x 17408 B
  const int tid = threadIdx.x;
  const int lane = tid & 63;
  const int n0 = blockIdx.x * 64;
  const int jb = RFL(tid >> 6) * JBLK;

  int n = n0 + lane;
  const bool valid = (n < N_NODES);
  if (!valid) n = N_NODES - 1;

  float acc[JBLK];
  #pragma unroll
  for (int j = 0; j < JBLK; ++j) acc[j] = bias[jb + j];

  #pragma unroll 1
  for (int tp = 0; tp < T_STEPS / 2; ++tp) {
    __syncthreads();
    float4 reg[8];
    #pragma unroll
    for (int it = 0; it < 8; ++it) {
      const int item = tid + it * 256;
      const int q = item & 15;
      const int u = (item >> 4) & 63;
      const int pl = item >> 10;
      reg[it] = *(const float4*)(sums + ((size_t)(2 * tp + pl) * N_PAD + n0 + u) * FDIM + q * 4);
    }
    #pragma unroll
    for (int it = 0; it < 8; ++it) {
      const int item = tid + it * 256;
      const int q = item & 15;
      const int u = (item >> 4) & 63;
      const int pl = item >> 10;
      *(float4*)(&lds[pl][u * PADF + q * 4]) = reg[it];
    }
    __syncthreads();

    #pragma unroll
    for (int pl = 0; pl < 2; ++pl) {
      const int t = 2 * tp + pl;

      const float c  = cnt[(size_t)t * N_NODES + n];
      const float rc = 1.0f / fmaxf(c, 1.0f);
      const float4* row = (const float4*)(&lds[pl][lane * PADF]);
      float ss = 0.0f;
      #pragma unroll
      for (int q = 0; q < FDIM / 4; ++q) {
        float4 v = row[q];
        float m0 = v.x * rc, m1 = v.y * rc, m2 = v.z * rc, m3 = v.w * rc;
        ss += m0 * m0 + m1 * m1 + m2 * m2 + m3 * m3;
      }
      const float norm = 1.0f - C2 * ss;
      const float s = rc / norm;

      #pragma unroll
      for (int q8 = 0; q8 < FDIM / 8; ++q8) {
        const float4 a = row[q8 * 2 + 0];
        const float4 b4 = row[q8 * 2 + 1];
        const float hv[8] = {a.x, a.y, a.z, a.w, b4.x, b4.y, b4.z, b4.w};
        const float* wr = W + ((size_t)t * FDIM + q8 * 8) * OUTF + jb;
        #pragma unroll
        for (int i = 0; i < 8; ++i) {
          const float hs = hv[i] * s;
          #pragma unroll
          for (int j = 0; j < JBLK; ++j)
            acc[j] = fmaf(hs, wr[i * OUTF + j], acc[j]);
        }
      }
    }
  }

  if (valid) {
    float* o = out + (size_t)n * OUTF + jb;
    #pragma unroll
    for (int j = 0; j < JBLK; ++j) o[j] = fmaxf(acc[j], 0.0f);
  }
}

extern "C" void kernel_launch(void* const* d_in, const int* in_sizes, int n_in,
                              void* d_out, int out_size, void* d_ws, size_t ws_size,
                              hipStream_t stream) {
  const float* x  = (const float*)d_in[0];
  const int*  ei  = (const int*)d_in[1];
  const int*  tix = (const int*)d_in[2];
  const float* W1 = (const float*)d_in[3];
  const float* b1 = (const float*)d_in[4];
  const float* W2 = (const float*)d_in[5];
  const float* b2 = (const float*)d_in[6];

  const int* src = ei;
  const int* dst = ei + N_EDGES;

  // Workspace: head[SEG] (2.4MB) | edat[NE] int2 (12.8MB) | sums[6*N_PAD*64]
  //          | cnt[SEG] | h1[N_PAD*64].  head+edat = 15.2MB = 256B-multiple,
  // so sums rows stay 256B-aligned (r21 lesson).
  int*   head = (int*)d_ws;
  int2*  edat = (int2*)(head + SEG);
  float* sums = (float*)(edat + N_EDGES);
  float* cnt  = sums + (size_t)T_STEPS * N_PAD * FDIM;
  float* h1   = cnt + SEG;

  const int sum_grid = (N_NODES + 3) / 4;        // k_sum6: 4 waves/block
  const int ngrp     = (N_NODES + 63) / 64;      // 1563 64-node groups

  hipMemsetAsync(head, 0xFF, (size_t)SEG * sizeof(int), stream);
  k_build<<<(N_EDGES + 255) / 256, 256, 0, stream>>>(src, dst, tix, head, edat);

  // Layer 1
  k_sum6<<<sum_grid, 256, 0, stream>>>(x, edat, head, sums, cnt);
  k_gemm_tile2<64, 16><<<ngrp, 256, 0, stream>>>(sums, cnt, W1, b1, h1);

  // Layer 2 (same edge lists; cnt identical but rewritten -- harmless)
  k_sum6<<<sum_grid, 256, 0, stream>>>(h1, edat, head, sums, cnt);
  k_gemm_tile2<16, 4><<<ngrp, 256, 0, stream>>>(sums, cnt, W2, b2, (float*)d_out);
}